// Round 1
// baseline (1908.994 us; speedup 1.0000x reference)
//
#include <hip/hip_runtime.h>
#include <cmath>
#include <cstdint>
#include <cstddef>
#include <climits>

#define N_SRC 65536
#define N_TGT 1024
#define DIM   256
#define TAU_INV (1.0f/0.07f)
#define LOSS_EPS 1e-6f
#define TOPSEL 512

// ---------------- top-5 insertion helpers (fully unrolled -> registers) -------------
__device__ __forceinline__ void insert5_vi(float v[5], int id[5], float nv, int ni) {
  // keep sorted desc by (value, then lower index) — matches stable argsort(-sim)
  bool beats_last = (nv > v[4]) || (nv == v[4] && ni < id[4]);
  if (!beats_last) return;
  #pragma unroll
  for (int p = 4; p > 0; --p) {
    bool up = (nv > v[p-1]) || (nv == v[p-1] && ni < id[p-1]);
    if (up) { v[p] = v[p-1]; id[p] = id[p-1]; }
    else    { v[p] = nv; id[p] = ni; return; }
  }
  v[0] = nv; id[0] = ni;
}

__device__ __forceinline__ void insert5_v(float v[5], float nv) {
  if (!(nv > v[4])) return;   // ties at boundary don't change a SUM
  #pragma unroll
  for (int p = 4; p > 0; --p) {
    if (nv > v[p-1]) v[p] = v[p-1];
    else { v[p] = nv; return; }
  }
  v[0] = nv;
}

// ---------------- K1: normalize targets (one wave per row) --------------------------
__global__ __launch_bounds__(256) void k_normalize_t(const float* __restrict__ T,
                                                     float* __restrict__ Tn) {
  int wave = threadIdx.x >> 6, lane = threadIdx.x & 63;
  int row  = blockIdx.x * 4 + wave;
  float4 v = reinterpret_cast<const float4*>(T + (size_t)row * DIM)[lane];
  float ss = v.x*v.x + v.y*v.y + v.z*v.z + v.w*v.w;
  #pragma unroll
  for (int o = 32; o > 0; o >>= 1) ss += __shfl_down(ss, o, 64);
  ss = __shfl(ss, 0, 64);
  float r = 1.0f / sqrtf(ss);
  float4 o4 = make_float4(v.x*r, v.y*r, v.z*r, v.w*r);
  reinterpret_cast<float4*>(Tn + (size_t)row * DIM)[lane] = o4;
}

// ---------------- K2: source inverse norms (one wave per row) -----------------------
__global__ __launch_bounds__(256) void k_src_invnorm(const float* __restrict__ S,
                                                     float* __restrict__ sinv) {
  int wave = threadIdx.x >> 6, lane = threadIdx.x & 63;
  int row  = blockIdx.x * 4 + wave;
  float4 v = reinterpret_cast<const float4*>(S + (size_t)row * DIM)[lane];
  float ss = v.x*v.x + v.y*v.y + v.z*v.z + v.w*v.w;
  #pragma unroll
  for (int o = 32; o > 0; o >>= 1) ss += __shfl_down(ss, o, 64);
  if (lane == 0) sinv[row] = 1.0f / sqrtf(ss);
}

// ---------------- K3: fp32 GEMM  simT[j][i] = (s_i . t_norm_j) * sinv_i -------------
#define BM 128
#define BN 128
#define BK 16

__global__ __launch_bounds__(256) void k_gemm_sim(
    const float* __restrict__ S, const float* __restrict__ Tn,
    const float* __restrict__ sinv, float* __restrict__ simT, int j_off)
{
  __shared__ float As[BK][BM];
  __shared__ float Bs[BK][BN];
  const int tid = threadIdx.x;
  const int i0  = blockIdx.x * BM;
  const int j0  = blockIdx.y * BN;         // local (within chunk)
  const int tx  = tid & 15;                // i direction
  const int ty  = tid >> 4;                // j direction
  const int lr  = tid >> 1;                // 0..127 (staging row)
  const int lc  = (tid & 1) * 8;           // 0 or 8 (staging k)

  float acc[8][8];
  #pragma unroll
  for (int a = 0; a < 8; ++a)
    #pragma unroll
    for (int b = 0; b < 8; ++b) acc[a][b] = 0.0f;

  const float* Aptr = S  + (size_t)(i0 + lr) * DIM + lc;
  const float* Bptr = Tn + (size_t)(j_off + j0 + lr) * DIM + lc;

  for (int k0 = 0; k0 < DIM; k0 += BK) {
    float4 a0 = *reinterpret_cast<const float4*>(Aptr + k0);
    float4 a1 = *reinterpret_cast<const float4*>(Aptr + k0 + 4);
    float4 b0 = *reinterpret_cast<const float4*>(Bptr + k0);
    float4 b1 = *reinterpret_cast<const float4*>(Bptr + k0 + 4);
    __syncthreads();
    As[lc+0][lr] = a0.x; As[lc+1][lr] = a0.y; As[lc+2][lr] = a0.z; As[lc+3][lr] = a0.w;
    As[lc+4][lr] = a1.x; As[lc+5][lr] = a1.y; As[lc+6][lr] = a1.z; As[lc+7][lr] = a1.w;
    Bs[lc+0][lr] = b0.x; Bs[lc+1][lr] = b0.y; Bs[lc+2][lr] = b0.z; Bs[lc+3][lr] = b0.w;
    Bs[lc+4][lr] = b1.x; Bs[lc+5][lr] = b1.y; Bs[lc+6][lr] = b1.z; Bs[lc+7][lr] = b1.w;
    __syncthreads();
    #pragma unroll
    for (int kk = 0; kk < BK; ++kk) {
      float4 a01 = *reinterpret_cast<const float4*>(&As[kk][tx*8]);
      float4 a23 = *reinterpret_cast<const float4*>(&As[kk][tx*8+4]);
      float4 b01 = *reinterpret_cast<const float4*>(&Bs[kk][ty*8]);
      float4 b23 = *reinterpret_cast<const float4*>(&Bs[kk][ty*8+4]);
      float av[8] = {a01.x,a01.y,a01.z,a01.w,a23.x,a23.y,a23.z,a23.w};
      float bv[8] = {b01.x,b01.y,b01.z,b01.w,b23.x,b23.y,b23.z,b23.w};
      #pragma unroll
      for (int jj = 0; jj < 8; ++jj)
        #pragma unroll
        for (int ii = 0; ii < 8; ++ii)
          acc[jj][ii] = fmaf(av[ii], bv[jj], acc[jj][ii]);
    }
  }

  float si[8];
  #pragma unroll
  for (int u = 0; u < 8; ++u) si[u] = sinv[i0 + tx*8 + u];
  #pragma unroll
  for (int jj = 0; jj < 8; ++jj) {
    float* dst = simT + (size_t)(j0 + ty*8 + jj) * N_SRC + i0 + tx*8;
    float4 o0 = make_float4(acc[jj][0]*si[0], acc[jj][1]*si[1],
                            acc[jj][2]*si[2], acc[jj][3]*si[3]);
    float4 o1 = make_float4(acc[jj][4]*si[4], acc[jj][5]*si[5],
                            acc[jj][6]*si[6], acc[jj][7]*si[7]);
    *reinterpret_cast<float4*>(dst)     = o0;
    *reinterpret_cast<float4*>(dst + 4) = o1;
  }
}

// ---------------- K4: per-column stats (one block per target column) ----------------
// scan 1: global top-5 (val,idx) -> assigned label (mode w/ reference tie-break)
// scan 2: top-5 matching, top-5 non-matching, sum(exp), sum(exp | match)
__global__ __launch_bounds__(256) void k_colstats(
    const float* __restrict__ simT, const int* __restrict__ labels,
    float* __restrict__ scores, float* __restrict__ contrast, int j_off)
{
  const int jloc = blockIdx.x;
  const float* row = simT + (size_t)jloc * N_SRC;
  const int tid = threadIdx.x;

  __shared__ float lv[256*5];
  __shared__ int   lid[256*5];
  __shared__ float mv[64*5];
  __shared__ int   mid[64*5];
  __shared__ float red[256];
  __shared__ int   s_assigned;
  __shared__ float s_sumall, s_summ;

  // ---- phase 1: top-5 overall ----
  float tv[5]; int tix[5];
  #pragma unroll
  for (int u = 0; u < 5; ++u) { tv[u] = -INFINITY; tix[u] = INT_MAX; }
  for (int i = tid; i < N_SRC; i += 256) insert5_vi(tv, tix, row[i], i);

  #pragma unroll
  for (int u = 0; u < 5; ++u) { lv[tid*5+u] = tv[u]; lid[tid*5+u] = tix[u]; }
  __syncthreads();
  if (tid < 64) {
    float v2[5]; int i2[5];
    #pragma unroll
    for (int u = 0; u < 5; ++u) { v2[u] = -INFINITY; i2[u] = INT_MAX; }
    for (int c = tid*20; c < tid*20 + 20; ++c) insert5_vi(v2, i2, lv[c], lid[c]);
    #pragma unroll
    for (int u = 0; u < 5; ++u) { mv[tid*5+u] = v2[u]; mid[tid*5+u] = i2[u]; }
  }
  __syncthreads();
  if (tid == 0) {
    float v3[5]; int i3[5];
    #pragma unroll
    for (int u = 0; u < 5; ++u) { v3[u] = -INFINITY; i3[u] = INT_MAX; }
    for (int c = 0; c < 320; ++c) insert5_vi(v3, i3, mv[c], mid[c]);
    int lab[5];
    #pragma unroll
    for (int a = 0; a < 5; ++a) lab[a] = labels[i3[a]];
    // mode with tie-break: argmax over (count*1e6 - label), first occurrence
    int bestSc = INT_MIN, bestA = 0;
    #pragma unroll
    for (int a = 0; a < 5; ++a) {
      int c = 0;
      #pragma unroll
      for (int b = 0; b < 5; ++b) c += (lab[b] == lab[a]) ? 1 : 0;
      int sc = c * 1000000 - lab[a];
      if (sc > bestSc) { bestSc = sc; bestA = a; }
    }
    s_assigned = lab[bestA];
  }
  __syncthreads();
  const int asg = s_assigned;

  // ---- phase 2 ----
  float mt[5], ut[5];
  #pragma unroll
  for (int u = 0; u < 5; ++u) { mt[u] = -INFINITY; ut[u] = -INFINITY; }
  float sall = 0.0f, sm = 0.0f;
  for (int i = tid; i < N_SRC; i += 256) {
    float val = row[i];
    float e = __expf(val * TAU_INV);
    sall += e;
    if (labels[i] == asg) { sm += e; insert5_v(mt, val); }
    else                  { insert5_v(ut, val); }
  }
  red[tid] = sall; __syncthreads();
  for (int s = 128; s > 0; s >>= 1) { if (tid < s) red[tid] += red[tid+s]; __syncthreads(); }
  if (tid == 0) s_sumall = red[0];
  __syncthreads();
  red[tid] = sm; __syncthreads();
  for (int s = 128; s > 0; s >>= 1) { if (tid < s) red[tid] += red[tid+s]; __syncthreads(); }
  if (tid == 0) s_summ = red[0];
  __syncthreads();

  // merge matching top-5
  #pragma unroll
  for (int u = 0; u < 5; ++u) lv[tid*5+u] = mt[u];
  __syncthreads();
  if (tid < 64) {
    float v2[5];
    #pragma unroll
    for (int u = 0; u < 5; ++u) v2[u] = -INFINITY;
    for (int c = tid*20; c < tid*20 + 20; ++c) insert5_v(v2, lv[c]);
    #pragma unroll
    for (int u = 0; u < 5; ++u) mv[tid*5+u] = v2[u];
  }
  __syncthreads();
  if (tid == 0) {
    float v3[5];
    #pragma unroll
    for (int u = 0; u < 5; ++u) v3[u] = -INFINITY;
    for (int c = 0; c < 320; ++c) insert5_v(v3, mv[c]);
    float nln = 0.0f;
    #pragma unroll
    for (int u = 0; u < 5; ++u) if (v3[u] > -1e30f) nln += v3[u];
    red[0] = nln;   // stash
  }
  __syncthreads();
  // merge non-matching top-5
  #pragma unroll
  for (int u = 0; u < 5; ++u) lv[tid*5+u] = ut[u];
  __syncthreads();
  if (tid < 64) {
    float v2[5];
    #pragma unroll
    for (int u = 0; u < 5; ++u) v2[u] = -INFINITY;
    for (int c = tid*20; c < tid*20 + 20; ++c) insert5_v(v2, lv[c]);
    #pragma unroll
    for (int u = 0; u < 5; ++u) mv[tid*5+u] = v2[u];
  }
  __syncthreads();
  if (tid == 0) {
    float v3[5];
    #pragma unroll
    for (int u = 0; u < 5; ++u) v3[u] = -INFINITY;
    for (int c = 0; c < 320; ++c) insert5_v(v3, mv[c]);
    float nun = 0.0f;
    #pragma unroll
    for (int u = 0; u < 5; ++u) if (v3[u] > -1e30f) nun += v3[u];
    float nln = red[0];
    scores[j_off + jloc]   = nln / nun;
    contrast[j_off + jloc] = s_summ / s_sumall;
  }
}

// ---------------- K5: top-512 selection (rank-based, index tie-break) + loss --------
__global__ __launch_bounds__(1024) void k_finalize(const float* __restrict__ scores,
                                                   const float* __restrict__ contrast,
                                                   float* __restrict__ out) {
  __shared__ float sc[N_TGT];
  __shared__ float red[N_TGT];
  const int j = threadIdx.x;
  sc[j] = scores[j];
  __syncthreads();
  float my = sc[j];
  int rank = 0;
  for (int m = 0; m < N_TGT; ++m) {
    float s = sc[m];
    rank += ((s > my) || (s == my && m < j)) ? 1 : 0;
  }
  red[j] = (rank < TOPSEL) ? logf(contrast[j] + LOSS_EPS) : 0.0f;
  __syncthreads();
  for (int s = 512; s > 0; s >>= 1) { if (j < s) red[j] += red[j+s]; __syncthreads(); }
  if (j == 0) out[0] = -red[0] / (float)TOPSEL;
}

// ---------------- launcher ----------------------------------------------------------
extern "C" void kernel_launch(void* const* d_in, const int* in_sizes, int n_in,
                              void* d_out, int out_size, void* d_ws, size_t ws_size,
                              hipStream_t stream) {
  const float* S      = (const float*)d_in[0];
  const int*   labels = (const int*)d_in[1];
  const float* T      = (const float*)d_in[2];
  float* out = (float*)d_out;

  float* ws = (float*)d_ws;
  float* t_norm    = ws;                          // N_TGT*DIM
  float* s_inv     = t_norm + (size_t)N_TGT*DIM;  // N_SRC
  float* scores    = s_inv + N_SRC;               // N_TGT
  float* contrastA = scores + N_TGT;              // N_TGT
  float* simbuf    = contrastA + N_TGT;           // the big one

  size_t head  = (size_t)(simbuf - ws);
  size_t avail = (ws_size / 4 > head) ? (ws_size / 4 - head) : 0;
  // column-chunking: pick the largest chunk that fits the workspace.
  // ws_size is constant across calls -> identical work each call (graph safe).
  int cols = 128;
  if      (avail >= (size_t)1024 * N_SRC) cols = 1024;
  else if (avail >= (size_t)512  * N_SRC) cols = 512;
  else if (avail >= (size_t)256  * N_SRC) cols = 256;

  k_normalize_t<<<N_TGT/4, 256, 0, stream>>>(T, t_norm);
  k_src_invnorm<<<N_SRC/4, 256, 0, stream>>>(S, s_inv);
  for (int j_off = 0; j_off < N_TGT; j_off += cols) {
    dim3 g(N_SRC / BM, cols / BN);
    k_gemm_sim<<<g, 256, 0, stream>>>(S, t_norm, s_inv, simbuf, j_off);
    k_colstats<<<cols, 256, 0, stream>>>(simbuf, labels, scores, contrastA, j_off);
  }
  k_finalize<<<1, 1024, 0, stream>>>(scores, contrastA, out);
}

// Round 2
// 1372.944 us; speedup vs baseline: 1.3904x; 1.3904x over previous
//
#include <hip/hip_runtime.h>
#include <cmath>
#include <cstdint>
#include <cstddef>
#include <climits>

#define N_SRC 65536
#define N_TGT 1024
#define DIM   256
#define TAU_INV (1.0f/0.07f)
#define LOSS_EPS 1e-6f
#define TOPSEL 512
#define NSLICE 8
#define SLICE_ELEMS (N_SRC / NSLICE)   // 8192

typedef __bf16 bf16x8 __attribute__((ext_vector_type(8)));
typedef float  f32x4  __attribute__((ext_vector_type(4)));

// ---------------- bf16 split helpers ------------------------------------------------
__device__ __forceinline__ unsigned short f2bf(float x) {
  unsigned u = __float_as_uint(x);
  unsigned r = (u + 0x7fffu + ((u >> 16) & 1u)) >> 16;
  return (unsigned short)r;
}
__device__ __forceinline__ float bf2f(unsigned short h) {
  return __uint_as_float(((unsigned)h) << 16);
}

// ---------------- top-5 insertion helpers -------------------------------------------
__device__ __forceinline__ void insert5_vi(float v[5], int id[5], float nv, int ni) {
  bool beats_last = (nv > v[4]) || (nv == v[4] && ni < id[4]);
  if (!beats_last) return;
  #pragma unroll
  for (int p = 4; p > 0; --p) {
    bool up = (nv > v[p-1]) || (nv == v[p-1] && ni < id[p-1]);
    if (up) { v[p] = v[p-1]; id[p] = id[p-1]; }
    else    { v[p] = nv; id[p] = ni; return; }
  }
  v[0] = nv; id[0] = ni;
}
__device__ __forceinline__ void insert5_v(float v[5], float nv) {
  if (!(nv > v[4])) return;
  #pragma unroll
  for (int p = 4; p > 0; --p) {
    if (nv > v[p-1]) v[p] = v[p-1];
    else { v[p] = nv; return; }
  }
  v[0] = nv;
}
// butterfly merge across the 64-lane wave: all lanes end with the wave's top-5
__device__ __forceinline__ void wave_merge5_vi(float v[5], int id[5]) {
  #pragma unroll
  for (int off = 1; off < 64; off <<= 1) {
    float pv[5]; int pi[5];
    #pragma unroll
    for (int u = 0; u < 5; ++u) {
      pv[u] = __shfl_xor(v[u], off, 64);
      pi[u] = __shfl_xor(id[u], off, 64);
    }
    #pragma unroll
    for (int u = 0; u < 5; ++u) insert5_vi(v, id, pv[u], pi[u]);
  }
}
__device__ __forceinline__ void wave_merge5_v(float v[5]) {
  #pragma unroll
  for (int off = 1; off < 64; off <<= 1) {
    float pv[5];
    #pragma unroll
    for (int u = 0; u < 5; ++u) pv[u] = __shfl_xor(v[u], off, 64);
    #pragma unroll
    for (int u = 0; u < 5; ++u) insert5_v(v, pv[u]);
  }
}

// ---------------- K1: normalize targets ---------------------------------------------
__global__ __launch_bounds__(256) void k_normalize_t(const float* __restrict__ T,
                                                     float* __restrict__ Tn) {
  int wave = threadIdx.x >> 6, lane = threadIdx.x & 63;
  int row  = blockIdx.x * 4 + wave;
  float4 v = reinterpret_cast<const float4*>(T + (size_t)row * DIM)[lane];
  float ss = v.x*v.x + v.y*v.y + v.z*v.z + v.w*v.w;
  #pragma unroll
  for (int o = 32; o > 0; o >>= 1) ss += __shfl_down(ss, o, 64);
  ss = __shfl(ss, 0, 64);
  float r = 1.0f / sqrtf(ss);
  reinterpret_cast<float4*>(Tn + (size_t)row * DIM)[lane] =
      make_float4(v.x*r, v.y*r, v.z*r, v.w*r);
}

// ---------------- K2: source inverse norms ------------------------------------------
__global__ __launch_bounds__(256) void k_src_invnorm(const float* __restrict__ S,
                                                     float* __restrict__ sinv) {
  int wave = threadIdx.x >> 6, lane = threadIdx.x & 63;
  int row  = blockIdx.x * 4 + wave;
  float4 v = reinterpret_cast<const float4*>(S + (size_t)row * DIM)[lane];
  float ss = v.x*v.x + v.y*v.y + v.z*v.z + v.w*v.w;
  #pragma unroll
  for (int o = 32; o > 0; o >>= 1) ss += __shfl_down(ss, o, 64);
  if (lane == 0) sinv[row] = 1.0f / sqrtf(ss);
}

// ---------------- K3: split fp32 -> (hi, lo) bf16 -----------------------------------
__global__ __launch_bounds__(256) void k_split(const float* __restrict__ x,
                                               unsigned short* __restrict__ hi,
                                               unsigned short* __restrict__ lo, int n4) {
  int idx = blockIdx.x * 256 + threadIdx.x;
  if (idx >= n4) return;
  float4 v = reinterpret_cast<const float4*>(x)[idx];
  ushort4 h, l;
  h.x = f2bf(v.x); l.x = f2bf(v.x - bf2f(h.x));
  h.y = f2bf(v.y); l.y = f2bf(v.y - bf2f(h.y));
  h.z = f2bf(v.z); l.z = f2bf(v.z - bf2f(h.z));
  h.w = f2bf(v.w); l.w = f2bf(v.w - bf2f(h.w));
  reinterpret_cast<ushort4*>(hi)[idx] = h;
  reinterpret_cast<ushort4*>(lo)[idx] = l;
}

// ---------------- K4: split-bf16 MFMA GEMM  simT[j][i] = (s_i . t_n_j) * sinv_i -----
// 128x128 tile, BK=32 bf16, 4 waves in 2x2, each wave 4x4 frags of 16x16x32.
// 3 MFMAs per frag pair: hi*hi + hi*lo + lo*hi  (lo*lo dropped, ~2^-16 rel).
__device__ __forceinline__ void gl_lds(const unsigned short* g, unsigned short* d) {
  __builtin_amdgcn_global_load_lds(
      (const __attribute__((address_space(1))) unsigned int*)g,
      (__attribute__((address_space(3))) unsigned int*)d, 16, 0, 0);
}

__global__ __launch_bounds__(256) void k_gemm(
    const unsigned short* __restrict__ Ahi, const unsigned short* __restrict__ Alo,
    const unsigned short* __restrict__ Bhi, const unsigned short* __restrict__ Blo,
    const float* __restrict__ sinv, float* __restrict__ simT, int j_off)
{
  __shared__ unsigned short As_hi[128*32];
  __shared__ unsigned short As_lo[128*32];
  __shared__ unsigned short Bs_hi[128*32];
  __shared__ unsigned short Bs_lo[128*32];

  const int tid  = threadIdx.x;
  const int lane = tid & 63;
  const int w    = tid >> 6;       // wave 0..3
  const int wm   = w & 1;          // src-dim half
  const int wn   = w >> 1;         // tgt-dim half
  const int i0   = blockIdx.x * 128;
  const int j0g  = j_off + blockIdx.y * 128;   // global target row (for B loads)
  const int j0l  = blockIdx.y * 128;           // chunk-local (for simT)

  f32x4 acc[4][4];
  #pragma unroll
  for (int a = 0; a < 4; ++a)
    #pragma unroll
    for (int b = 0; b < 4; ++b) acc[a][b] = f32x4{0.f, 0.f, 0.f, 0.f};

  // staging addresses: wave w covers rows [w*32, w*32+32), 16 rows per instruction
  const int srow = (w << 5) + (lane >> 2);
  const int scol = (lane & 3) << 3;             // element offset (8 bf16 = 16 B)
  const unsigned short* gAh = Ahi + (size_t)(i0  + srow) * DIM + scol;
  const unsigned short* gAl = Alo + (size_t)(i0  + srow) * DIM + scol;
  const unsigned short* gBh = Bhi + (size_t)(j0g + srow) * DIM + scol;
  const unsigned short* gBl = Blo + (size_t)(j0g + srow) * DIM + scol;
  unsigned short* dA0 = &As_hi[(w << 5) * 32];
  unsigned short* dA1 = &As_hi[((w << 5) + 16) * 32];
  unsigned short* dB0 = &Bs_hi[(w << 5) * 32];
  unsigned short* dB1 = &Bs_hi[((w << 5) + 16) * 32];
  unsigned short* dA0l = &As_lo[(w << 5) * 32];
  unsigned short* dA1l = &As_lo[((w << 5) + 16) * 32];
  unsigned short* dB0l = &Bs_lo[(w << 5) * 32];
  unsigned short* dB1l = &Bs_lo[((w << 5) + 16) * 32];

  const int fr = lane & 15;            // fragment row (m or n)
  const int fk = (lane >> 4) << 3;     // fragment k offset

  for (int k0 = 0; k0 < DIM; k0 += 32) {
    __syncthreads();   // previous compute done before LDS overwrite
    gl_lds(gAh + k0,           dA0);
    gl_lds(gAh + k0 + 16*DIM,  dA1);
    gl_lds(gAl + k0,           dA0l);
    gl_lds(gAl + k0 + 16*DIM,  dA1l);
    gl_lds(gBh + k0,           dB0);
    gl_lds(gBh + k0 + 16*DIM,  dB1);
    gl_lds(gBl + k0,           dB0l);
    gl_lds(gBl + k0 + 16*DIM,  dB1l);
    __syncthreads();   // compiler drains vmcnt before s_barrier

    bf16x8 ah[4], al[4], bh[4], bl[4];
    #pragma unroll
    for (int rf = 0; rf < 4; ++rf) {
      int r = ((wm << 6) + (rf << 4) + fr) * 32 + fk;
      ah[rf] = *(const bf16x8*)&As_hi[r];
      al[rf] = *(const bf16x8*)&As_lo[r];
    }
    #pragma unroll
    for (int cf = 0; cf < 4; ++cf) {
      int r = ((wn << 6) + (cf << 4) + fr) * 32 + fk;
      bh[cf] = *(const bf16x8*)&Bs_hi[r];
      bl[cf] = *(const bf16x8*)&Bs_lo[r];
    }
    #pragma unroll
    for (int rf = 0; rf < 4; ++rf)
      #pragma unroll
      for (int cf = 0; cf < 4; ++cf) {
        acc[rf][cf] = __builtin_amdgcn_mfma_f32_16x16x32_bf16(ah[rf], bh[cf], acc[rf][cf], 0, 0, 0);
        acc[rf][cf] = __builtin_amdgcn_mfma_f32_16x16x32_bf16(ah[rf], bl[cf], acc[rf][cf], 0, 0, 0);
        acc[rf][cf] = __builtin_amdgcn_mfma_f32_16x16x32_bf16(al[rf], bh[cf], acc[rf][cf], 0, 0, 0);
      }
  }

  // epilogue: D[m][n] lane mapping n = lane&15, m = (lane>>4)*4 + reg
  #pragma unroll
  for (int rf = 0; rf < 4; ++rf) {
    const int m_base = (wm << 6) + (rf << 4) + ((lane >> 4) << 2);
    const float4 sv = *reinterpret_cast<const float4*>(&sinv[i0 + m_base]);
    #pragma unroll
    for (int cf = 0; cf < 4; ++cf) {
      const int n = (wn << 6) + (cf << 4) + (lane & 15);
      float4 o = make_float4(acc[rf][cf][0] * sv.x, acc[rf][cf][1] * sv.y,
                             acc[rf][cf][2] * sv.z, acc[rf][cf][3] * sv.w);
      *reinterpret_cast<float4*>(&simT[(size_t)(j0l + n) * N_SRC + i0 + m_base]) = o;
    }
  }
}

// ---------------- K5: per-slice top-5 (val,idx) partials ----------------------------
__global__ __launch_bounds__(256) void k_part1(const float* __restrict__ simT,
                                               float* __restrict__ p1v, int* __restrict__ p1i,
                                               int j_off) {
  const int s    = blockIdx.x;     // slice 0..7
  const int jloc = blockIdx.y;
  const int tid  = threadIdx.x;
  const int lane = tid & 63, w = tid >> 6;
  const float4* row = reinterpret_cast<const float4*>(simT + (size_t)jloc * N_SRC)
                      + s * (SLICE_ELEMS/4) + tid;
  float tv[5]; int tix[5];
  #pragma unroll
  for (int u = 0; u < 5; ++u) { tv[u] = -INFINITY; tix[u] = INT_MAX; }
  const int base = s * SLICE_ELEMS + tid * 4;
  #pragma unroll
  for (int t = 0; t < 8; ++t) {
    float4 v = row[t * 256];
    int bi = base + t * 1024;
    insert5_vi(tv, tix, v.x, bi);
    insert5_vi(tv, tix, v.y, bi + 1);
    insert5_vi(tv, tix, v.z, bi + 2);
    insert5_vi(tv, tix, v.w, bi + 3);
  }
  wave_merge5_vi(tv, tix);
  __shared__ float wv[4*5]; __shared__ int wi[4*5];
  if (lane == 0) {
    #pragma unroll
    for (int u = 0; u < 5; ++u) { wv[w*5+u] = tv[u]; wi[w*5+u] = tix[u]; }
  }
  __syncthreads();
  if (tid == 0) {
    float v3[5]; int i3[5];
    #pragma unroll
    for (int u = 0; u < 5; ++u) { v3[u] = -INFINITY; i3[u] = INT_MAX; }
    for (int c = 0; c < 20; ++c) insert5_vi(v3, i3, wv[c], wi[c]);
    const size_t o = ((size_t)(j_off + jloc) * NSLICE + s) * 5;
    #pragma unroll
    for (int u = 0; u < 5; ++u) { p1v[o+u] = v3[u]; p1i[o+u] = i3[u]; }
  }
}

// ---------------- K6: merge slices -> assigned label per column ---------------------
__global__ __launch_bounds__(64) void k_assign(const float* __restrict__ p1v,
                                               const int* __restrict__ p1i,
                                               const int* __restrict__ labels,
                                               int* __restrict__ assigned, int j_off) {
  const int j = j_off + blockIdx.x * 64 + threadIdx.x;
  float v[5]; int id[5];
  #pragma unroll
  for (int u = 0; u < 5; ++u) { v[u] = -INFINITY; id[u] = INT_MAX; }
  for (int c = 0; c < NSLICE * 5; ++c)
    insert5_vi(v, id, p1v[(size_t)j * NSLICE * 5 + c], p1i[(size_t)j * NSLICE * 5 + c]);
  int lab[5];
  #pragma unroll
  for (int a = 0; a < 5; ++a) lab[a] = labels[id[a]];
  int bestSc = INT_MIN, bestA = 0;
  #pragma unroll
  for (int a = 0; a < 5; ++a) {
    int c = 0;
    #pragma unroll
    for (int b = 0; b < 5; ++b) c += (lab[b] == lab[a]) ? 1 : 0;
    int sc = c * 1000000 - lab[a];
    if (sc > bestSc) { bestSc = sc; bestA = a; }
  }
  assigned[j] = lab[bestA];
}

// ---------------- K7: per-slice label-conditional partials --------------------------
__global__ __launch_bounds__(256) void k_part2(const float* __restrict__ simT,
                                               const int* __restrict__ labels,
                                               const int* __restrict__ assigned,
                                               float* __restrict__ p2mt, float* __restrict__ p2ut,
                                               float* __restrict__ p2s,  float* __restrict__ p2sm,
                                               int j_off) {
  const int s    = blockIdx.x;
  const int jloc = blockIdx.y;
  const int tid  = threadIdx.x;
  const int lane = tid & 63, w = tid >> 6;
  const int asg  = assigned[j_off + jloc];
  const float4* row = reinterpret_cast<const float4*>(simT + (size_t)jloc * N_SRC)
                      + s * (SLICE_ELEMS/4) + tid;
  const int4* lab4 = reinterpret_cast<const int4*>(labels) + s * (SLICE_ELEMS/4) + tid;

  float mt[5], ut[5];
  #pragma unroll
  for (int u = 0; u < 5; ++u) { mt[u] = -INFINITY; ut[u] = -INFINITY; }
  float sall = 0.f, sm = 0.f;
  #pragma unroll
  for (int t = 0; t < 8; ++t) {
    float4 v = row[t * 256];
    int4   l = lab4[t * 256];
    float ex = __expf(v.x * TAU_INV); sall += ex;
    if (l.x == asg) { sm += ex; insert5_v(mt, v.x); } else insert5_v(ut, v.x);
    float ey = __expf(v.y * TAU_INV); sall += ey;
    if (l.y == asg) { sm += ey; insert5_v(mt, v.y); } else insert5_v(ut, v.y);
    float ez = __expf(v.z * TAU_INV); sall += ez;
    if (l.z == asg) { sm += ez; insert5_v(mt, v.z); } else insert5_v(ut, v.z);
    float ew = __expf(v.w * TAU_INV); sall += ew;
    if (l.w == asg) { sm += ew; insert5_v(mt, v.w); } else insert5_v(ut, v.w);
  }
  #pragma unroll
  for (int o = 32; o > 0; o >>= 1) { sall += __shfl_xor(sall, o, 64); sm += __shfl_xor(sm, o, 64); }
  wave_merge5_v(mt);
  wave_merge5_v(ut);
  __shared__ float wmt[4*5], wut[4*5], wsa[4], wsm[4];
  if (lane == 0) {
    #pragma unroll
    for (int u = 0; u < 5; ++u) { wmt[w*5+u] = mt[u]; wut[w*5+u] = ut[u]; }
    wsa[w] = sall; wsm[w] = sm;
  }
  __syncthreads();
  if (tid == 0) {
    float m3[5], u3[5];
    #pragma unroll
    for (int u = 0; u < 5; ++u) { m3[u] = -INFINITY; u3[u] = -INFINITY; }
    for (int c = 0; c < 20; ++c) { insert5_v(m3, wmt[c]); insert5_v(u3, wut[c]); }
    float sa = wsa[0]+wsa[1]+wsa[2]+wsa[3], smm = wsm[0]+wsm[1]+wsm[2]+wsm[3];
    const size_t o = ((size_t)(j_off + jloc) * NSLICE + s) * 5;
    #pragma unroll
    for (int u = 0; u < 5; ++u) { p2mt[o+u] = m3[u]; p2ut[o+u] = u3[u]; }
    p2s [(size_t)(j_off + jloc) * NSLICE + s] = sa;
    p2sm[(size_t)(j_off + jloc) * NSLICE + s] = smm;
  }
}

// ---------------- K8: merge slices -> scores, contrast ------------------------------
__global__ __launch_bounds__(64) void k_score(const float* __restrict__ p2mt,
                                              const float* __restrict__ p2ut,
                                              const float* __restrict__ p2s,
                                              const float* __restrict__ p2sm,
                                              float* __restrict__ scores,
                                              float* __restrict__ contrast, int j_off) {
  const int j = j_off + blockIdx.x * 64 + threadIdx.x;
  float mt[5], ut[5];
  #pragma unroll
  for (int u = 0; u < 5; ++u) { mt[u] = -INFINITY; ut[u] = -INFINITY; }
  for (int c = 0; c < NSLICE * 5; ++c) {
    insert5_v(mt, p2mt[(size_t)j * NSLICE * 5 + c]);
    insert5_v(ut, p2ut[(size_t)j * NSLICE * 5 + c]);
  }
  float sa = 0.f, sm = 0.f;
  #pragma unroll
  for (int s = 0; s < NSLICE; ++s) { sa += p2s[(size_t)j*NSLICE+s]; sm += p2sm[(size_t)j*NSLICE+s]; }
  float nln = 0.f, nun = 0.f;
  #pragma unroll
  for (int u = 0; u < 5; ++u) {
    if (mt[u] > -1e30f) nln += mt[u];
    if (ut[u] > -1e30f) nun += ut[u];
  }
  scores[j]   = nln / nun;
  contrast[j] = sm / sa;
}

// ---------------- K9: top-512 selection + loss --------------------------------------
__global__ __launch_bounds__(1024) void k_finalize(const float* __restrict__ scores,
                                                   const float* __restrict__ contrast,
                                                   float* __restrict__ out) {
  __shared__ float sc[N_TGT];
  __shared__ float red[N_TGT];
  const int j = threadIdx.x;
  sc[j] = scores[j];
  __syncthreads();
  float my = sc[j];
  int rank = 0;
  for (int m = 0; m < N_TGT; ++m) {
    float s = sc[m];
    rank += ((s > my) || (s == my && m < j)) ? 1 : 0;
  }
  red[j] = (rank < TOPSEL) ? logf(contrast[j] + LOSS_EPS) : 0.0f;
  __syncthreads();
  for (int s = 512; s > 0; s >>= 1) { if (j < s) red[j] += red[j+s]; __syncthreads(); }
  if (j == 0) out[0] = -red[0] / (float)TOPSEL;
}

// ---------------- launcher ----------------------------------------------------------
extern "C" void kernel_launch(void* const* d_in, const int* in_sizes, int n_in,
                              void* d_out, int out_size, void* d_ws, size_t ws_size,
                              hipStream_t stream) {
  const float* S      = (const float*)d_in[0];
  const int*   labels = (const int*)d_in[1];
  const float* T      = (const float*)d_in[2];
  float* out = (float*)d_out;

  float* ws = (float*)d_ws;
  float* t_norm    = ws;                             // 262144
  float* s_inv     = t_norm + (size_t)N_TGT*DIM;     // 65536
  float* scores    = s_inv + N_SRC;                  // 1024
  float* contrastA = scores + N_TGT;                 // 1024
  int*   assigned  = (int*)(contrastA + N_TGT);      // 1024
  float* p1v       = (float*)(assigned + N_TGT);     // 40960
  int*   p1i       = (int*)(p1v + N_TGT*NSLICE*5);   // 40960
  float* p2mt      = (float*)(p1i + N_TGT*NSLICE*5); // 40960
  float* p2ut      = p2mt + N_TGT*NSLICE*5;          // 40960
  float* p2s       = p2ut + N_TGT*NSLICE*5;          // 8192
  float* p2sm      = p2s + N_TGT*NSLICE;             // 8192
  unsigned short* Shi = (unsigned short*)(p2sm + N_TGT*NSLICE); // 65536*256 ush
  unsigned short* Slo = Shi + (size_t)N_SRC*DIM;
  unsigned short* Thi = Slo + (size_t)N_SRC*DIM;     // 1024*256 ush
  unsigned short* Tlo = Thi + (size_t)N_TGT*DIM;
  float* simbuf       = (float*)(Tlo + (size_t)N_TGT*DIM);

  size_t head  = (size_t)((float*)simbuf - ws);
  size_t avail = (ws_size / 4 > head) ? (ws_size / 4 - head) : 0;
  int cols = 128;
  if      (avail >= (size_t)1024 * N_SRC) cols = 1024;
  else if (avail >= (size_t)512  * N_SRC) cols = 512;
  else if (avail >= (size_t)256  * N_SRC) cols = 256;

  k_normalize_t<<<N_TGT/4, 256, 0, stream>>>(T, t_norm);
  k_src_invnorm<<<N_SRC/4, 256, 0, stream>>>(S, s_inv);
  k_split<<<(N_SRC*DIM/4 + 255)/256, 256, 0, stream>>>(S, Shi, Slo, N_SRC*DIM/4);
  k_split<<<(N_TGT*DIM/4 + 255)/256, 256, 0, stream>>>(t_norm, Thi, Tlo, N_TGT*DIM/4);

  for (int j_off = 0; j_off < N_TGT; j_off += cols) {
    dim3 gg(N_SRC / 128, cols / 128);
    k_gemm<<<gg, 256, 0, stream>>>(Shi, Slo, Thi, Tlo, s_inv, simbuf, j_off);
    dim3 gp(NSLICE, cols);
    k_part1<<<gp, 256, 0, stream>>>(simbuf, p1v, p1i, j_off);
    k_assign<<<cols/64, 64, 0, stream>>>(p1v, p1i, labels, assigned, j_off);
    k_part2<<<gp, 256, 0, stream>>>(simbuf, labels, assigned, p2mt, p2ut, p2s, p2sm, j_off);
    k_score<<<cols/64, 64, 0, stream>>>(p2mt, p2ut, p2s, p2sm, scores, contrastA, j_off);
  }
  k_finalize<<<1, 1024, 0, stream>>>(scores, contrastA, out);
}